// Round 1
// 149.151 us; speedup vs baseline: 1.0059x; 1.0059x over previous
//
#include <hip/hip_runtime.h>
#include <hip/hip_bf16.h>

// FenwickLogLinearAttention: B=2,T=2048,C=1024,H=16,Dh=64
// R4: gemm_qkv rewritten as 8-phase counted-vmcnt schedule (T2+T3+T4+T5),
//     tile 256x192 (grid 16x16 = 256 blocks = 1/CU), BK=64, dbuf LDS 112KB.
//     vmcnt(5) only at phases 4/8 (3 partial-tiles in flight); raw s_barrier,
//     no vmcnt(0) drain in main loop. prep/attn/proj unchanged.
// ws layout (bytes): xb@0 (8M) | WqkvT@8M (6M) | QKVb@14M (24M) | AO@38M (8M) | WprojT@46M (2M)

typedef unsigned short ushort_t;
typedef __attribute__((ext_vector_type(8))) short s16x8;
typedef __attribute__((ext_vector_type(4))) float f32x4;

#define T_SEQ 2048
#define C_DIM 1024
#define HEADS 16

__device__ __forceinline__ ushort_t f2bf(float f) {
    union { float f; unsigned u; } v{f};
    unsigned r = v.u + 0x7FFFu + ((v.u >> 16) & 1u);   // RNE
    return (ushort_t)(r >> 16);
}
__device__ __forceinline__ float bf2f(ushort_t u) {
    union { unsigned u; float f; } v{((unsigned)u) << 16};
    return v.f;
}

__device__ __forceinline__ void async16(const ushort_t* g, ushort_t* l) {
    __builtin_amdgcn_global_load_lds(
        (const __attribute__((address_space(1))) void*)g,
        (__attribute__((address_space(3))) void*)l, 16, 0, 0);
}

// ---------------- merged prep: cvt(x)->bf16 + two weight transposes ----------------
__global__ void prep(const float* __restrict__ x, ushort_t* __restrict__ xb,
                     const float* __restrict__ Wq, ushort_t* __restrict__ WqT,
                     const float* __restrict__ Wp, ushort_t* __restrict__ WpT) {
    const int bid = blockIdx.x;
    const int tid = threadIdx.x;
    if (bid < 4096) {
        const int i = bid * 256 + tid;
        float4 f = ((const float4*)x)[i];
        ushort4 o;
        o.x = f2bf(f.x); o.y = f2bf(f.y); o.z = f2bf(f.z); o.w = f2bf(f.w);
        ((ushort4*)xb)[i] = o;
    } else {
        __shared__ ushort_t tile[32][33];
        const float* W; ushort_t* WT; int N, nb, kb;
        if (bid < 7168) {
            const int tb = bid - 4096;
            W = Wq; WT = WqT; N = 3072; nb = (tb % 96) * 32; kb = (tb / 96) * 32;
        } else {
            const int tb = bid - 7168;
            W = Wp; WT = WpT; N = 1024; nb = (tb & 31) * 32; kb = (tb >> 5) * 32;
        }
        const int tx = tid & 31, ty = tid >> 5;
        #pragma unroll
        for (int i = ty; i < 32; i += 8)
            tile[i][tx] = f2bf(W[(size_t)(kb + i) * N + nb + tx]);
        __syncthreads();
        #pragma unroll
        for (int i = ty; i < 32; i += 8)
            WT[(size_t)(nb + i) * 1024 + kb + tx] = tile[tx][i];
    }
}

// ---------------- QKV GEMM: 256x192 tile, BK=64, 8-phase counted-vmcnt ----------------
// C[M][N] = A[M][K] @ BT[N][K]^T + bias[N], bf16 out. 512 thr = 8 waves (2M x 4N),
// per-wave 128x48 output, acc[8][3]. LDS: 2 x (A 256x64 + B 192x64) bf16 = 112 KiB.
// Swizzle: LDS slot s of row r holds global k-group s ^ (r&7) (linear dest +
// pre-swizzled global source; read XORs the slot).

#define BAR()  do { __builtin_amdgcn_sched_barrier(0); __builtin_amdgcn_s_barrier(); \
                    __builtin_amdgcn_sched_barrier(0); } while (0)
#define WAIT_LGKM0() do { asm volatile("s_waitcnt lgkmcnt(0)" ::: "memory"); \
                          __builtin_amdgcn_sched_barrier(0); } while (0)
#define WAIT_VM(n)  asm volatile("s_waitcnt vmcnt(" #n ")" ::: "memory")

#define SA(kt, u, dst) async16(Ag + (size_t)(u) * rstep + (size_t)(kt) * 64, \
                               (dst) + (u) * 4096 + wave * 512)
#define SB(kt, u, dst) async16(Bg + (size_t)(u) * rstep + (size_t)(kt) * 64, \
                               (dst) + (u) * 4096 + wave * 512)

#define LDA_FRAG(buf, i, kh) (*(const s16x8*)((buf) + ((wm << 7) + (i) * 16 + lrow) * 64 \
                               + ((((kh) * 4 + quad) ^ d3) << 3)))
#define LDB_FRAG(buf, j, kh) (*(const s16x8*)((buf) + (wn * 48 + (j) * 16 + lrow) * 64 \
                               + ((((kh) * 4 + quad) ^ d3) << 3)))

// one phase: quadrant Q (M-frags 2Q,2Q+1) x all 3 N-frags x K=64 (12 MFMA)
#define PHASE(lAb, lBb, Q, LOADB, STAGES, ENDWAIT)                              \
  {                                                                             \
    s16x8 af[2][2];                                                             \
    _Pragma("unroll") for (int ii = 0; ii < 2; ++ii)                            \
      _Pragma("unroll") for (int kh = 0; kh < 2; ++kh)                          \
        af[ii][kh] = LDA_FRAG(lAb, 2 * (Q) + ii, kh);                           \
    if (LOADB) {                                                                \
      _Pragma("unroll") for (int j = 0; j < 3; ++j)                             \
        _Pragma("unroll") for (int kh = 0; kh < 2; ++kh)                        \
          bf[j][kh] = LDB_FRAG(lBb, j, kh);                                     \
    }                                                                           \
    STAGES;                                                                     \
    BAR();                                                                      \
    WAIT_LGKM0();                                                               \
    __builtin_amdgcn_s_setprio(1);                                              \
    _Pragma("unroll") for (int ii = 0; ii < 2; ++ii)                            \
      _Pragma("unroll") for (int j = 0; j < 3; ++j)                             \
        _Pragma("unroll") for (int kh = 0; kh < 2; ++kh)                        \
          acc[2 * (Q) + ii][j] = __builtin_amdgcn_mfma_f32_16x16x32_bf16(       \
              af[ii][kh], bf[j][kh], acc[2 * (Q) + ii][j], 0, 0, 0);            \
    __builtin_amdgcn_s_setprio(0);                                              \
    ENDWAIT;                                                                    \
    BAR();                                                                      \
  }

__global__ __launch_bounds__(512, 2)
void gemm_qkv(const ushort_t* __restrict__ A, const ushort_t* __restrict__ BT,
              const float* __restrict__ bias, ushort_t* __restrict__ C,
              int N, int K) {
    __shared__ ushort_t lds[57344];          // 112 KiB

    const int tid  = threadIdx.x;
    const int wave = tid >> 6;
    const int lane = tid & 63;
    const int wm   = wave >> 2;              // 0..1  (M half)
    const int wn   = wave & 3;               // 0..3  (N quarter: 48 cols)
    const int lrow = lane & 15;
    const int quad = lane >> 4;
    const int d3   = lrow & 7;
    const int crow = lane >> 3;
    const int gcol = (((lane & 7) ^ crow) << 3);   // pre-swizzled global k-group
    const int row0 = blockIdx.x * 256;
    const int col0 = blockIdx.y * 192;

    ushort_t* const lA0 = lds;                       // A buf0: 16384 el
    ushort_t* const lB0 = lds + 16384;               // B buf0: 12288 el
    ushort_t* const lA1 = lds + 28672;               // A buf1
    ushort_t* const lB1 = lds + 45056;               // B buf1

    const ushort_t* Ag = A  + (size_t)(row0 + wave * 8 + crow) * K + gcol;
    const ushort_t* Bg = BT + (size_t)(col0 + wave * 8 + crow) * K + gcol;
    const size_t rstep = (size_t)64 * K;             // 64-row stage unit

    f32x4 acc[8][3] = {};
    s16x8 bf[3][2];

    // prologue: tile0 fully (7 loads), tile1 partial (5: B01,A02,B2) -> vmcnt(5)
    SA(0, 0, lA0); SA(0, 1, lA0); SA(0, 2, lA0); SA(0, 3, lA0);
    SB(0, 0, lB0); SB(0, 1, lB0); SB(0, 2, lB0);
    SB(1, 0, lB1); SB(1, 1, lB1); SA(1, 0, lA1); SA(1, 2, lA1); SB(1, 2, lB1);
    WAIT_VM(5);
    BAR();

    const int nt = K >> 6;                           // 16 K-tiles
    for (int t = 0; t < nt; t += 2) {
        const bool s2 = (t + 2) < nt;
        const bool s3 = (t + 3) < nt;
        // ph1: compute q0 of tile t (buf0); finish staging tile t+1 (A u1,u3)
        PHASE(lA0, lB0, 0, true,  { SA(t + 1, 1, lA1); SA(t + 1, 3, lA1); }, {});
        // ph2: q1; stage B(t+2) u0,u1 (buf0 B free after ph1)
        PHASE(lA0, lB0, 1, false, { if (s2) { SB(t + 2, 0, lB0); SB(t + 2, 1, lB0); } }, {});
        // ph3: q2; stage A(t+2) u0,u2 (rows 0-63/128-191 free after ph2)
        PHASE(lA0, lB0, 2, false, { if (s2) { SA(t + 2, 0, lA0); SA(t + 2, 2, lA0); } }, {});
        // ph4: q3; stage B(t+2) u2; counted wait -> tile t+1 fully landed
        PHASE(lA0, lB0, 3, false, { if (s2) { SB(t + 2, 2, lB0); } },
              { if (s2) { WAIT_VM(5); } else { WAIT_VM(0); } });
        // ph5: q0 of tile t+1 (buf1); stage A(t+2) u1,u3 (rows 64-127/192-255 free after ph4)
        PHASE(lA1, lB1, 0, true,  { if (s2) { SA(t + 2, 1, lA0); SA(t + 2, 3, lA0); } }, {});
        // ph6: q1; stage B(t+3) u0,u1
        PHASE(lA1, lB1, 1, false, { if (s3) { SB(t + 3, 0, lB1); SB(t + 3, 1, lB1); } }, {});
        // ph7: q2; stage A(t+3) u0,u2
        PHASE(lA1, lB1, 2, false, { if (s3) { SA(t + 3, 0, lA1); SA(t + 3, 2, lA1); } }, {});
        // ph8: q3; stage B(t+3) u2; counted wait -> tile t+2 fully landed
        PHASE(lA1, lB1, 3, false, { if (s3) { SB(t + 3, 2, lB1); } },
              { WAIT_VM(5); });
    }

    // D mapping: col=lane&15, row=quad*4+reg (m89-verified)
    #pragma unroll
    for (int i = 0; i < 8; ++i) {
        #pragma unroll
        for (int j = 0; j < 3; ++j) {
            const int col = col0 + wn * 48 + j * 16 + lrow;
            const float bv = bias[col];
            #pragma unroll
            for (int r = 0; r < 4; ++r) {
                const int row = row0 + (wm << 7) + i * 16 + quad * 4 + r;
                C[(size_t)row * N + col] = f2bf(acc[i][j][r] + bv);
            }
        }
    }
}

// ---------------- proj GEMM: 128x64 tile, BK=64, swizzled LDS, fp32 out ----------------
__global__ void gemm_proj(const ushort_t* __restrict__ A, const ushort_t* __restrict__ BT,
                          const float* __restrict__ bias, float* __restrict__ C,
                          int N, int K) {
    __shared__ ushort_t lsA[128 * 64];
    __shared__ ushort_t lsB[64 * 64];

    const int tid  = threadIdx.x;
    const int wave = tid >> 6;
    const int lane = tid & 63;
    const int row0 = blockIdx.x * 128;
    const int col0 = blockIdx.y * 64;
    const int lrow = lane & 15;
    const int quad = lane >> 4;
    const int crow = lane >> 3;
    const int gcol = ((lane & 7) ^ crow) * 8;
    const int d3   = lrow & 7;

    f32x4 acc[2][4] = {};

    for (int k0 = 0; k0 < K; k0 += 64) {
        #pragma unroll
        for (int it = 0; it < 4; ++it) {
            const int chunk = it * 4 + wave;           // A: 16 chunks
            const int r = chunk * 8 + crow;
            async16(A + (size_t)(row0 + r) * K + (k0 + gcol), lsA + chunk * 512);
        }
        #pragma unroll
        for (int it = 0; it < 2; ++it) {
            const int chunk = it * 4 + wave;           // B: 8 chunks
            const int r = chunk * 8 + crow;
            async16(BT + (size_t)(col0 + r) * K + (k0 + gcol), lsB + chunk * 512);
        }
        __syncthreads();
        #pragma unroll
        for (int kk = 0; kk < 64; kk += 32) {
            const int g = (kk >> 3) + quad;
            const int slot = (g ^ d3) << 3;
            s16x8 af[2], bfr[4];
            #pragma unroll
            for (int i = 0; i < 2; ++i)
                af[i] = *(const s16x8*)(lsA + (wave * 32 + i * 16 + lrow) * 64 + slot);
            #pragma unroll
            for (int j = 0; j < 4; ++j)
                bfr[j] = *(const s16x8*)(lsB + (j * 16 + lrow) * 64 + slot);
            #pragma unroll
            for (int i = 0; i < 2; ++i)
                #pragma unroll
                for (int j = 0; j < 4; ++j)
                    acc[i][j] = __builtin_amdgcn_mfma_f32_16x16x32_bf16(
                        af[i], bfr[j], acc[i][j], 0, 0, 0);
        }
        __syncthreads();
    }

    #pragma unroll
    for (int i = 0; i < 2; ++i) {
        #pragma unroll
        for (int j = 0; j < 4; ++j) {
            const int col = col0 + j * 16 + lrow;
            const float bv = bias[col];
            #pragma unroll
            for (int r = 0; r < 4; ++r) {
                const int row = row0 + wave * 32 + i * 16 + quad * 4 + r;
                C[(size_t)row * N + col] = acc[i][j][r] + bv;
            }
        }
    }
}

// ---------------- sparse Fenwick attention ----------------
__global__ void fenwick_attn(const ushort_t* __restrict__ QKV, ushort_t* __restrict__ AO) {
    const int lane = threadIdx.x & 63;
    const int wid  = blockIdx.x * 4 + (threadIdx.x >> 6);
    const int tile = wid & 255;
    const int bh   = wid >> 8;
    const int h    = bh & (HEADS - 1);
    const int b    = bh >> 4;
    const int tl   = lane >> 3;
    const int g    = lane & 7;
    const int t    = tile * 8 + tl;

    const ushort_t* base = QKV + (size_t)(b * T_SEQ) * 3072 + h * 64 + g * 8;

    float qf[8];
    {
        s16x8 qv = *(const s16x8*)(base + (size_t)t * 3072);
        #pragma unroll
        for (int e = 0; e < 8; ++e) qf[e] = bf2f((ushort_t)qv[e]);
    }

    float logit[12];
    int   pos[12];
    float mx = -1e30f;
    #pragma unroll
    for (int s = 0; s < 12; ++s) {
        const int step = (s == 0) ? 0 : (1 << (s - 1));
        const bool act = (step <= t);
        const int p = act ? (t - step) : t;
        pos[s] = p;
        s16x8 kv = *(const s16x8*)(base + (size_t)p * 3072 + 1024);
        float l = 0.f;
        #pragma unroll
        for (int e = 0; e < 8; ++e) l = fmaf(qf[e], bf2f((ushort_t)kv[e]), l);
        l += __shfl_xor(l, 1, 64);
        l += __shfl_xor(l, 2, 64);
        l += __shfl_xor(l, 4, 64);
        l *= 0.125f;                       // Dh^-0.5
        logit[s] = act ? l : -1e30f;
        mx = fmaxf(mx, logit[s]);
    }

    float denom = 0.f;
    float ov[8] = {};
    #pragma unroll
    for (int s = 0; s < 12; ++s) {
        const float w = __expf(logit[s] - mx);
        denom += w;
        s16x8 vv = *(const s16x8*)(base + (size_t)pos[s] * 3072 + 2048);
        #pragma unroll
        for (int e = 0; e < 8; ++e) ov[e] = fmaf(w, bf2f((ushort_t)vv[e]), ov[e]);
    }

    const float inv = 1.f / denom;
    s16x8 os;
    #pragma unroll
    for (int e = 0; e < 8; ++e) os[e] = (short)f2bf(ov[e] * inv);
    *(s16x8*)(AO + (size_t)(b * T_SEQ + t) * C_DIM + h * 64 + g * 8) = os;
}

extern "C" void kernel_launch(void* const* d_in, const int* in_sizes, int n_in,
                              void* d_out, int out_size, void* d_ws, size_t ws_size,
                              hipStream_t stream) {
    const float* x      = (const float*)d_in[0];
    const float* W_qkv  = (const float*)d_in[1];
    const float* b_qkv  = (const float*)d_in[2];
    const float* W_proj = (const float*)d_in[3];
    const float* b_proj = (const float*)d_in[4];
    float* out = (float*)d_out;

    char* ws = (char*)d_ws;
    ushort_t* xb     = (ushort_t*)(ws);                        // 4096x1024 bf16
    ushort_t* WqkvT  = (ushort_t*)(ws + (size_t)8  * 1048576); // 3072x1024 bf16
    ushort_t* QKVb   = (ushort_t*)(ws + (size_t)14 * 1048576); // 4096x3072 bf16
    ushort_t* AO     = (ushort_t*)(ws + (size_t)38 * 1048576); // 4096x1024 bf16
    ushort_t* WprojT = (ushort_t*)(ws + (size_t)46 * 1048576); // 1024x1024 bf16

    prep<<<8192, 256, 0, stream>>>(x, xb, W_qkv, WqkvT, W_proj, WprojT);
    gemm_qkv<<<dim3(16, 16), 512, 0, stream>>>(xb, WqkvT, b_qkv, QKVb, 3072, 1024);
    fenwick_attn<<<2048, 256, 0, stream>>>(QKVb, AO);
    gemm_proj<<<dim3(32, 16), 256, 0, stream>>>(AO, WprojT, b_proj, out, 1024, 1024);
}